// Round 6
// baseline (218.826 us; speedup 1.0000x reference)
//
#include <hip/hip_runtime.h>

#define NPTS   8192
#define NB     256          // one block per CU (capacity-guaranteed co-residency)
#define NT     256
#define CHUNK  4096         // dst points staged in LDS per pass (64 KB)
#define NCHUNK (NPTS / CHUNK)
#define CSTEPS (CHUNK / 64) // 64 inner steps per chunk per lane
#define MAXIT  20
#define TOLER  1e-3
#define SPINCAP 200000000u  // hang guard

typedef unsigned long long u64;
typedef unsigned int u32;

// ---- ws byte-offset layout (~164 KB) ----
#define WS_BP      0            // float4[8192]  (2bx,2by,2bz,|b|^2)  131072 B
#define WS_PART    131072       // double[NB][16]                      32768 B
#define WS_SCAL    163840       // double[13]: prev_err, T(12)           104 B
#define WS_FLAGS   163944       // int[2]: done, T_iter                    8 B
#define WS_CNT     163952       // int[MAXIT+1]: election counters        84 B

__device__ inline double atom_ld(const double* p) {
  return __hip_atomic_load(p, __ATOMIC_RELAXED, __HIP_MEMORY_SCOPE_AGENT);
}
__device__ inline void atom_st(double* p, double v) {
  __hip_atomic_store(p, v, __ATOMIC_RELAXED, __HIP_MEMORY_SCOPE_AGENT);
}
__device__ inline int atom_ldi(const int* p) {
  return __hip_atomic_load(p, __ATOMIC_RELAXED, __HIP_MEMORY_SCOPE_AGENT);
}
__device__ inline void atom_sti(int* p, int v) {
  __hip_atomic_store(p, v, __ATOMIC_RELAXED, __HIP_MEMORY_SCOPE_AGENT);
}

// Kabsch rotation from 3x3 cross-covariance H (double, single-thread):
// H = U S V^T (numpy convention), R = V' U^T with last V column flipped if
// det(V U^T) < 0 — matches the reference's Vt-last-row flip exactly.
__device__ void kabsch_R(const double H[3][3], double R[3][3])
{
  double K[3][3]; // H^T H = V S^2 V^T
  for (int i = 0; i < 3; ++i)
    for (int j = 0; j < 3; ++j) {
      double s = 0.0;
      for (int k = 0; k < 3; ++k) s += H[k][i] * H[k][j];
      K[i][j] = s;
    }
  double V[3][3] = {{1,0,0},{0,1,0},{0,0,1}};
  for (int sweep = 0; sweep < 30; ++sweep) {
    double off = K[0][1]*K[0][1] + K[0][2]*K[0][2] + K[1][2]*K[1][2];
    double dia = K[0][0]*K[0][0] + K[1][1]*K[1][1] + K[2][2]*K[2][2];
    if (off <= 1e-28 * (dia + 1e-300)) break;
    for (int pi = 0; pi < 3; ++pi) {
      const int p = (pi == 2) ? 1 : 0;
      const int q = (pi == 0) ? 1 : 2;
      double apq = K[p][q];
      if (fabs(apq) < 1e-300) continue;
      double theta = (K[q][q] - K[p][p]) / (2.0 * apq);
      double t = ((theta >= 0.0) ? 1.0 : -1.0) / (fabs(theta) + sqrt(1.0 + theta*theta));
      double c = 1.0 / sqrt(1.0 + t*t);
      double s = t * c;
      double kpp = K[p][p], kqq = K[q][q];
      K[p][p] = kpp - t * apq;
      K[q][q] = kqq + t * apq;
      K[p][q] = 0.0; K[q][p] = 0.0;
      const int r = 3 - p - q;
      double krp = K[r][p], krq = K[r][q];
      K[r][p] = c*krp - s*krq; K[p][r] = K[r][p];
      K[r][q] = s*krp + c*krq; K[q][r] = K[r][q];
      for (int k = 0; k < 3; ++k) {
        double vkp = V[k][p], vkq = V[k][q];
        V[k][p] = c*vkp - s*vkq;
        V[k][q] = s*vkp + c*vkq;
      }
    }
  }
  double w[3] = {K[0][0], K[1][1], K[2][2]};
  for (int a = 0; a < 2; ++a)          // sort descending (numpy sv order)
    for (int b = 0; b < 2 - a; ++b)
      if (w[b] < w[b+1]) {
        double tw = w[b]; w[b] = w[b+1]; w[b+1] = tw;
        for (int k = 0; k < 3; ++k) { double tv = V[k][b]; V[k][b] = V[k][b+1]; V[k][b+1] = tv; }
      }
  double U[3][3]; // columns u_k = normalize(H v_k)
  for (int k = 0; k < 3; ++k) {
    double u0 = H[0][0]*V[0][k] + H[0][1]*V[1][k] + H[0][2]*V[2][k];
    double u1 = H[1][0]*V[0][k] + H[1][1]*V[1][k] + H[1][2]*V[2][k];
    double u2 = H[2][0]*V[0][k] + H[2][1]*V[1][k] + H[2][2]*V[2][k];
    double n = sqrt(u0*u0 + u1*u1 + u2*u2);
    if (n > 1e-150) { u0 /= n; u1 /= n; u2 /= n; }
    else if (k == 2) { // degenerate smallest sv: complete basis
      u0 = U[1][0]*U[2][1] - U[2][0]*U[1][1];
      u1 = U[2][0]*U[0][1] - U[0][0]*U[2][1];
      u2 = U[0][0]*U[1][1] - U[1][0]*U[0][1];
      double n2 = sqrt(u0*u0 + u1*u1 + u2*u2) + 1e-300;
      u0 /= n2; u1 /= n2; u2 /= n2;
    } else {
      u0 = (k == 0) ? 1.0 : 0.0; u1 = (k == 1) ? 1.0 : 0.0; u2 = 0.0;
    }
    U[0][k] = u0; U[1][k] = u1; U[2][k] = u2;
  }
  double R0[3][3]; // V U^T
  for (int i = 0; i < 3; ++i)
    for (int j = 0; j < 3; ++j)
      R0[i][j] = V[i][0]*U[j][0] + V[i][1]*U[j][1] + V[i][2]*U[j][2];
  double det = R0[0][0]*(R0[1][1]*R0[2][2] - R0[1][2]*R0[2][1])
             - R0[0][1]*(R0[1][0]*R0[2][2] - R0[1][2]*R0[2][0])
             + R0[0][2]*(R0[1][0]*R0[2][1] - R0[1][1]*R0[2][0]);
  if (det < 0.0)
    for (int i = 0; i < 3; ++i)
      for (int j = 0; j < 3; ++j)
        R0[i][j] -= 2.0 * V[i][2] * U[j][2]; // flip last column of V
  for (int i = 0; i < 3; ++i)
    for (int j = 0; j < 3; ++j)
      R[i][j] = R0[i][j];
}

// 32 x 256 = 8192 threads: precompute Bp, zero flags/counters
__global__ void icp_init(const float* __restrict__ B, char* __restrict__ ws)
{
  int t = blockIdx.x * NT + threadIdx.x; // 0..8191
  float bx = B[3*t], by = B[3*t+1], bz = B[3*t+2];
  ((float4*)(ws + WS_BP))[t] =
      make_float4(2.f*bx, 2.f*by, 2.f*bz, bx*bx + by*by + bz*bz);
  if (t < MAXIT + 1) ((int*)(ws + WS_CNT))[t] = 0;
  if (t == 0) {
    double* scal = (double*)(ws + WS_SCAL);
    int* flags = (int*)(ws + WS_FLAGS);
    scal[0] = 0.0;   // prev_err
    flags[0] = 0;    // done
    flags[1] = -1;   // T_iter (generation flag for the spin barrier)
  }
}

// Persistent kernel: all 20 ICP iterations + final best-fit in one dispatch.
// block b owns src points b*32..b*32+31 (wave w: 8 of them, in registers).
__global__ __launch_bounds__(NT, 1)
void icp_all(const float* __restrict__ A, const float* __restrict__ B,
             char* __restrict__ ws, float* __restrict__ out)
{
  const float4* __restrict__ Bp = (const float4*)(ws + WS_BP);
  double* partials = (double*)(ws + WS_PART);
  double* scal     = (double*)(ws + WS_SCAL);
  int*    flags    = (int*)(ws + WS_FLAGS);
  int*    cnt      = (int*)(ws + WS_CNT);

  __shared__ __align__(16) unsigned char smem[CHUNK * 16]; // 64 KB
  float4* bp_lds = (float4*)smem;                 // NN staging
  double* red1   = (double*)smem;                 // [32][16] leader rows
  double* red2   = (double*)(smem + 32*16*8);     // [4][16] wave sums
  float*  Tl     = (float*)(smem + 36*16*8);      // broadcast: T(12)
  int*    dl     = (int*)(smem + 36*16*8 + 48);   // broadcast: done
  __shared__ int iswin;

  const int tid  = threadIdx.x;
  const int blk  = blockIdx.x;
  const int wav  = tid >> 6;
  const int lane = tid & 63;
  const int qbase = blk * 32 + wav * 8; // this wave's 8 src points

  float ax[8], ay[8], az[8], sx[8], sy[8], sz[8];
  #pragma unroll
  for (int i = 0; i < 8; ++i) { // broadcast loads: all lanes hold all 8 src
    int p = qbase + i;
    ax[i] = A[3*p]; ay[i] = A[3*p+1]; az[i] = A[3*p+2];
    sx[i] = ax[i];  sy[i] = ay[i];    sz[i] = az[i];
  }

  for (int it = 0; it < MAXIT; ++it) {
    // ---- brute-force 1-NN: LDS-staged dst, 8 src per LDS read ----
    float emin[8]; int imin[8];
    #pragma unroll
    for (int i = 0; i < 8; ++i) { emin[i] = 3.4e38f; imin[i] = 0; }

    for (int c = 0; c < NCHUNK; ++c) {
      __syncthreads(); // LDS reuse (prev iter red1/Tl or prev chunk)
      for (int i = tid; i < CHUNK; i += NT)   // float4 copy from L2-hot Bp
        bp_lds[i] = Bp[c * CHUNK + i];
      __syncthreads();
      const int jbase = c * CHUNK + lane;
      #pragma unroll 8
      for (int stp = 0; stp < CSTEPS; ++stp) {
        float4 d = bp_lds[stp * 64 + lane];
        int jg = jbase + stp * 64;
        #pragma unroll
        for (int i = 0; i < 8; ++i) {
          // e = |b|^2 - 2 s.b ; argmin_j e == argmin_j d2 (d2 = e + |s|^2)
          float e = fmaf(-sx[i], d.x, fmaf(-sy[i], d.y, fmaf(-sz[i], d.z, d.w)));
          if (e < emin[i]) { emin[i] = e; imin[i] = jg; } // strict < => 1st idx
        }
      }
    }
    // wave argmin butterfly (lowest index wins ties)
    #pragma unroll
    for (int m = 1; m < 64; m <<= 1) {
      #pragma unroll
      for (int i = 0; i < 8; ++i) {
        float eo = __shfl_xor(emin[i], m, 64);
        int   io = __shfl_xor(imin[i], m, 64);
        if (eo < emin[i] || (eo == emin[i] && io < imin[i])) { emin[i] = eo; imin[i] = io; }
      }
    }

    __syncthreads(); // all bp_lds reads done before LDS reuse as red1
    #pragma unroll
    for (int i = 0; i < 8; ++i) {
      if (lane == i) { // leader lane i handles src point qbase+i
        float s2 = sx[i]*sx[i] + sy[i]*sy[i] + sz[i]*sz[i];
        float d2 = emin[i] + s2;
        float dist = sqrtf(fmaxf(d2, 0.f) + 1e-12f);
        int j = imin[i];
        float bx = B[3*j], by = B[3*j+1], bz = B[3*j+2];
        double* r = red1 + (wav * 8 + i) * 16;
        r[0]=sx[i]; r[1]=sy[i]; r[2]=sz[i];
        r[3]=bx;    r[4]=by;    r[5]=bz;
        r[6]=(double)sx[i]*bx;  r[7]=(double)sx[i]*by;  r[8]=(double)sx[i]*bz;
        r[9]=(double)sy[i]*bx;  r[10]=(double)sy[i]*by; r[11]=(double)sy[i]*bz;
        r[12]=(double)sz[i]*bx; r[13]=(double)sz[i]*by; r[14]=(double)sz[i]*bz;
        r[15]=dist;
      }
    }
    __syncthreads();
    if (tid < 16) {
      double ssum = 0.0;
      for (int g = 0; g < 32; ++g) ssum += red1[g * 16 + tid];
      atom_st(&partials[(size_t)blk * 16 + tid], ssum);
    }
    __threadfence();      // release partials before election arrival
    __syncthreads();
    if (tid == 0) iswin = (atomicAdd(&cnt[it], 1) == NB - 1);
    __syncthreads();

    if (iswin) { // ---- winner block: reduce 256 partials, solve, publish ----
      __threadfence();    // acquire other blocks' partials
      double a2[16];
      #pragma unroll
      for (int k = 0; k < 16; ++k)
        a2[k] = atom_ld(&partials[(size_t)tid * 16 + k]); // one row per thread
      for (int m = 1; m < 64; m <<= 1) {
        #pragma unroll
        for (int k = 0; k < 16; ++k) a2[k] += __shfl_xor(a2[k], m, 64);
      }
      if (lane == 0)
        for (int k = 0; k < 16; ++k) red2[wav * 16 + k] = a2[k];
      __syncthreads();
      if (tid == 0) {
        double S[16];
        for (int k = 0; k < 16; ++k)
          S[k] = red2[k] + red2[16+k] + red2[32+k] + red2[48+k];
        const double invN = 1.0 / NPTS;
        double cAv[3] = {S[0]*invN, S[1]*invN, S[2]*invN};
        double cBv[3] = {S[3]*invN, S[4]*invN, S[5]*invN};
        double H[3][3];
        for (int i = 0; i < 3; ++i)
          for (int j = 0; j < 3; ++j)
            H[i][j] = S[6 + i*3 + j] - (double)NPTS * cAv[i] * cBv[j];
        double err = S[15] * invN;
        double prev_err = atom_ld(&scal[0]);
        int conv = (fabs(prev_err - err) < TOLER) ? 1 : 0;
        double R[3][3];
        kabsch_R(H, R);
        double t0 = cBv[0] - (R[0][0]*cAv[0] + R[0][1]*cAv[1] + R[0][2]*cAv[2]);
        double t1 = cBv[1] - (R[1][0]*cAv[0] + R[1][1]*cAv[1] + R[1][2]*cAv[2]);
        double t2 = cBv[2] - (R[2][0]*cAv[0] + R[2][1]*cAv[1] + R[2][2]*cAv[2]);
        atom_st(&scal[1], R[0][0]); atom_st(&scal[2], R[0][1]); atom_st(&scal[3], R[0][2]);
        atom_st(&scal[4], R[1][0]); atom_st(&scal[5], R[1][1]); atom_st(&scal[6], R[1][2]);
        atom_st(&scal[7], R[2][0]); atom_st(&scal[8], R[2][1]); atom_st(&scal[9], R[2][2]);
        atom_st(&scal[10], t0); atom_st(&scal[11], t1); atom_st(&scal[12], t2);
        atom_st(&scal[0], err);
        atom_sti(&flags[0], conv);
        __threadfence();               // release T/err/done ...
        atom_sti(&flags[1], it);       // ... then open generation `it`
      }
    }

    // ---- spin barrier: wait for this iteration's T ----
    if (tid == 0) {
      u32 spins = 0;
      while (atom_ldi(&flags[1]) < it && spins < SPINCAP) {
        __builtin_amdgcn_s_sleep(1);
        ++spins;
      }
      __threadfence();                 // acquire published scal/flags
      for (int k = 0; k < 12; ++k) Tl[k] = (float)atom_ld(&scal[1 + k]);
      *dl = atom_ldi(&flags[0]);
    }
    __syncthreads();

    { // apply T in fp32 (ref: new_src = T @ src in fp32, before done latches)
      float r00=Tl[0],r01=Tl[1],r02=Tl[2],r10=Tl[3],r11=Tl[4],r12=Tl[5];
      float r20=Tl[6],r21=Tl[7],r22=Tl[8],t0=Tl[9],t1=Tl[10],t2=Tl[11];
      int done = *dl;
      #pragma unroll
      for (int i = 0; i < 8; ++i) {
        float nx = r00*sx[i] + r01*sy[i] + r02*sz[i] + t0;
        float ny = r10*sx[i] + r11*sy[i] + r12*sz[i] + t1;
        float nz = r20*sx[i] + r21*sy[i] + r22*sz[i] + t2;
        sx[i]=nx; sy[i]=ny; sz[i]=nz;
      }
      if (done) break; // uniform decision across all blocks
    }
  }

  // ---- final best_fit_transform(A, src): H = sum a (x) s - N cA cS^T ----
  __syncthreads(); // LDS reuse (Tl/red1)
  #pragma unroll
  for (int i = 0; i < 8; ++i) {
    if (lane == i) {
      double* r = red1 + (wav * 8 + i) * 16;
      r[0]=ax[i]; r[1]=ay[i]; r[2]=az[i];
      r[3]=sx[i]; r[4]=sy[i]; r[5]=sz[i];
      r[6]=(double)ax[i]*sx[i];  r[7]=(double)ax[i]*sy[i];  r[8]=(double)ax[i]*sz[i];
      r[9]=(double)ay[i]*sx[i];  r[10]=(double)ay[i]*sy[i]; r[11]=(double)ay[i]*sz[i];
      r[12]=(double)az[i]*sx[i]; r[13]=(double)az[i]*sy[i]; r[14]=(double)az[i]*sz[i];
      r[15]=0.0;
    }
  }
  __syncthreads();
  if (tid < 16) {
    double ssum = 0.0;
    for (int g = 0; g < 32; ++g) ssum += red1[g * 16 + tid];
    atom_st(&partials[(size_t)blk * 16 + tid], ssum);
  }
  __threadfence();
  __syncthreads();
  if (tid == 0) iswin = (atomicAdd(&cnt[MAXIT], 1) == NB - 1);
  __syncthreads();
  if (!iswin) return;
  __threadfence();

  double a2[16];
  #pragma unroll
  for (int k = 0; k < 16; ++k)
    a2[k] = atom_ld(&partials[(size_t)tid * 16 + k]);
  for (int m = 1; m < 64; m <<= 1) {
    #pragma unroll
    for (int k = 0; k < 16; ++k) a2[k] += __shfl_xor(a2[k], m, 64);
  }
  if (lane == 0)
    for (int k = 0; k < 16; ++k) red2[wav * 16 + k] = a2[k];
  __syncthreads();
  if (tid == 0) {
    double S[16];
    for (int k = 0; k < 16; ++k)
      S[k] = red2[k] + red2[16+k] + red2[32+k] + red2[48+k];
    const double invN = 1.0 / NPTS;
    double cAv[3] = {S[0]*invN, S[1]*invN, S[2]*invN};
    double cSv[3] = {S[3]*invN, S[4]*invN, S[5]*invN};
    double H[3][3];
    for (int i = 0; i < 3; ++i)
      for (int j = 0; j < 3; ++j)
        H[i][j] = S[6 + i*3 + j] - (double)NPTS * cAv[i] * cSv[j];
    double R[3][3];
    kabsch_R(H, R);
    double u0 = cSv[0] - (R[0][0]*cAv[0] + R[0][1]*cAv[1] + R[0][2]*cAv[2]);
    double u1 = cSv[1] - (R[1][0]*cAv[0] + R[1][1]*cAv[1] + R[1][2]*cAv[2]);
    double u2 = cSv[2] - (R[2][0]*cAv[0] + R[2][1]*cAv[1] + R[2][2]*cAv[2]);
    out[0]=(float)R[0][0]; out[1]=(float)R[0][1]; out[2]=(float)R[0][2]; out[3]=(float)u0;
    out[4]=(float)R[1][0]; out[5]=(float)R[1][1]; out[6]=(float)R[1][2]; out[7]=(float)u1;
    out[8]=(float)R[2][0]; out[9]=(float)R[2][1]; out[10]=(float)R[2][2]; out[11]=(float)u2;
    out[12]=0.f; out[13]=0.f; out[14]=0.f; out[15]=1.f;
  }
}

extern "C" void kernel_launch(void* const* d_in, const int* in_sizes, int n_in,
                              void* d_out, int out_size, void* d_ws, size_t ws_size,
                              hipStream_t stream) {
  const float* A = (const float*)d_in[0];
  const float* B = (const float*)d_in[1];
  float* out = (float*)d_out;
  char* ws = (char*)d_ws; // needs ~164 KB

  hipLaunchKernelGGL(icp_init, dim3(NPTS / NT), dim3(NT), 0, stream, B, ws);
  hipLaunchKernelGGL(icp_all, dim3(NB), dim3(NT), 0, stream, A, B, ws, out);
}

// Round 7
// 190.074 us; speedup vs baseline: 1.1513x; 1.1513x over previous
//
#include <hip/hip_runtime.h>

#define NPTS   8192
#define NB     256          // one block per CU (128KB LDS => 1 block/CU)
#define NT     256
#define NSTEP  (NPTS / 64)  // 128 inner steps per lane (full dst sweep)
#define MAXIT  20
#define TOLER  1e-3
#define SPINCAP 200000000u  // hang guard

typedef unsigned long long u64;
typedef unsigned int u32;

// ---- ws byte-offset layout (~66 KB) ----
#define WS_PART    0        // double[2][NB][16] parity-buffered   65536 B
#define WS_CNT     65536    // int[MAXIT+1]: arrival counters         84 B

__device__ inline double atom_ld(const double* p) {
  return __hip_atomic_load(p, __ATOMIC_RELAXED, __HIP_MEMORY_SCOPE_AGENT);
}
__device__ inline void atom_st(double* p, double v) {
  __hip_atomic_store(p, v, __ATOMIC_RELAXED, __HIP_MEMORY_SCOPE_AGENT);
}
__device__ inline int atom_ldi(const int* p) {
  return __hip_atomic_load(p, __ATOMIC_RELAXED, __HIP_MEMORY_SCOPE_AGENT);
}

// Kabsch rotation from 3x3 cross-covariance H (double, single-thread):
// H = U S V^T (numpy convention), R = V' U^T with last V column flipped if
// det(V U^T) < 0 — matches the reference's Vt-last-row flip exactly.
__device__ void kabsch_R(const double H[3][3], double R[3][3])
{
  double K[3][3]; // H^T H = V S^2 V^T
  for (int i = 0; i < 3; ++i)
    for (int j = 0; j < 3; ++j) {
      double s = 0.0;
      for (int k = 0; k < 3; ++k) s += H[k][i] * H[k][j];
      K[i][j] = s;
    }
  double V[3][3] = {{1,0,0},{0,1,0},{0,0,1}};
  for (int sweep = 0; sweep < 30; ++sweep) {
    double off = K[0][1]*K[0][1] + K[0][2]*K[0][2] + K[1][2]*K[1][2];
    double dia = K[0][0]*K[0][0] + K[1][1]*K[1][1] + K[2][2]*K[2][2];
    if (off <= 1e-28 * (dia + 1e-300)) break;
    for (int pi = 0; pi < 3; ++pi) {
      const int p = (pi == 2) ? 1 : 0;
      const int q = (pi == 0) ? 1 : 2;
      double apq = K[p][q];
      if (fabs(apq) < 1e-300) continue;
      double theta = (K[q][q] - K[p][p]) / (2.0 * apq);
      double t = ((theta >= 0.0) ? 1.0 : -1.0) / (fabs(theta) + sqrt(1.0 + theta*theta));
      double c = 1.0 / sqrt(1.0 + t*t);
      double s = t * c;
      double kpp = K[p][p], kqq = K[q][q];
      K[p][p] = kpp - t * apq;
      K[q][q] = kqq + t * apq;
      K[p][q] = 0.0; K[q][p] = 0.0;
      const int r = 3 - p - q;
      double krp = K[r][p], krq = K[r][q];
      K[r][p] = c*krp - s*krq; K[p][r] = K[r][p];
      K[r][q] = s*krp + c*krq; K[q][r] = K[r][q];
      for (int k = 0; k < 3; ++k) {
        double vkp = V[k][p], vkq = V[k][q];
        V[k][p] = c*vkp - s*vkq;
        V[k][q] = s*vkp + c*vkq;
      }
    }
  }
  double w[3] = {K[0][0], K[1][1], K[2][2]};
  for (int a = 0; a < 2; ++a)          // sort descending (numpy sv order)
    for (int b = 0; b < 2 - a; ++b)
      if (w[b] < w[b+1]) {
        double tw = w[b]; w[b] = w[b+1]; w[b+1] = tw;
        for (int k = 0; k < 3; ++k) { double tv = V[k][b]; V[k][b] = V[k][b+1]; V[k][b+1] = tv; }
      }
  double U[3][3]; // columns u_k = normalize(H v_k)
  for (int k = 0; k < 3; ++k) {
    double u0 = H[0][0]*V[0][k] + H[0][1]*V[1][k] + H[0][2]*V[2][k];
    double u1 = H[1][0]*V[0][k] + H[1][1]*V[1][k] + H[1][2]*V[2][k];
    double u2 = H[2][0]*V[0][k] + H[2][1]*V[1][k] + H[2][2]*V[2][k];
    double n = sqrt(u0*u0 + u1*u1 + u2*u2);
    if (n > 1e-150) { u0 /= n; u1 /= n; u2 /= n; }
    else if (k == 2) { // degenerate smallest sv: complete basis
      u0 = U[1][0]*U[2][1] - U[2][0]*U[1][1];
      u1 = U[2][0]*U[0][1] - U[0][0]*U[2][1];
      u2 = U[0][0]*U[1][1] - U[1][0]*U[0][1];
      double n2 = sqrt(u0*u0 + u1*u1 + u2*u2) + 1e-300;
      u0 /= n2; u1 /= n2; u2 /= n2;
    } else {
      u0 = (k == 0) ? 1.0 : 0.0; u1 = (k == 1) ? 1.0 : 0.0; u2 = 0.0;
    }
    U[0][k] = u0; U[1][k] = u1; U[2][k] = u2;
  }
  double R0[3][3]; // V U^T
  for (int i = 0; i < 3; ++i)
    for (int j = 0; j < 3; ++j)
      R0[i][j] = V[i][0]*U[j][0] + V[i][1]*U[j][1] + V[i][2]*U[j][2];
  double det = R0[0][0]*(R0[1][1]*R0[2][2] - R0[1][2]*R0[2][1])
             - R0[0][1]*(R0[1][0]*R0[2][2] - R0[1][2]*R0[2][0])
             + R0[0][2]*(R0[1][0]*R0[2][1] - R0[1][1]*R0[2][0]);
  if (det < 0.0)
    for (int i = 0; i < 3; ++i)
      for (int j = 0; j < 3; ++j)
        R0[i][j] -= 2.0 * V[i][2] * U[j][2]; // flip last column of V
  for (int i = 0; i < 3; ++i)
    for (int j = 0; j < 3; ++j)
      R[i][j] = R0[i][j];
}

__global__ void icp_init(char* __restrict__ ws)
{
  int t = threadIdx.x;
  if (t < MAXIT + 1) ((int*)(ws + WS_CNT))[t] = 0;
}

// Persistent kernel: Bp staged into LDS ONCE; all 20 iterations + final
// best-fit. block b owns src points b*32..b*32+31 (wave w: 8, in registers).
// Every block redundantly reduces+solves (deterministic => identical T/done).
__global__ __launch_bounds__(NT, 1)
void icp_all(const float* __restrict__ A, const float* __restrict__ B,
             char* __restrict__ ws, float* __restrict__ out)
{
  double* partials = (double*)(ws + WS_PART);
  int*    cnt      = (int*)(ws + WS_CNT);

  __shared__ __align__(16) float4 bp_lds[NPTS];   // 128 KB, persistent
  __shared__ double red1[32 * 16];                // 4 KB leader rows
  __shared__ double red2[4 * 16];                 // wave sums
  __shared__ float  Tl[12];
  __shared__ int    dl;

  const int tid  = threadIdx.x;
  const int blk  = blockIdx.x;
  const int wav  = tid >> 6;
  const int lane = tid & 63;
  const int qbase = blk * 32 + wav * 8; // this wave's 8 src points

  // ---- stage Bp once (B is constant across all iterations) ----
  for (int i = tid; i < NPTS; i += NT) {
    float bx = B[3*i], by = B[3*i+1], bz = B[3*i+2];
    bp_lds[i] = make_float4(2.f*bx, 2.f*by, 2.f*bz, bx*bx + by*by + bz*bz);
  }

  float ax[8], ay[8], az[8], sx[8], sy[8], sz[8];
  #pragma unroll
  for (int i = 0; i < 8; ++i) { // broadcast loads: all lanes hold all 8 src
    int p = qbase + i;
    ax[i] = A[3*p]; ay[i] = A[3*p+1]; az[i] = A[3*p+2];
    sx[i] = ax[i];  sy[i] = ay[i];    sz[i] = az[i];
  }
  __syncthreads(); // bp_lds ready

  double prev_err = 0.0; // tid0-meaningful; identical on every block
  int it = 0;
  for (; it < MAXIT; ++it) {
    const int par = it & 1;
    // ---- brute-force 1-NN: persistent LDS dst, no barriers in the scan ----
    float emin[8]; int imin[8];
    #pragma unroll
    for (int i = 0; i < 8; ++i) { emin[i] = 3.4e38f; imin[i] = 0; }

    #pragma unroll 4
    for (int stp = 0; stp < NSTEP; ++stp) {
      float4 d = bp_lds[stp * 64 + lane];
      int jg = stp * 64 + lane;
      #pragma unroll
      for (int i = 0; i < 8; ++i) {
        // e = |b|^2 - 2 s.b ; argmin_j e == argmin_j d2 (d2 = e + |s|^2)
        float e = fmaf(-sx[i], d.x, fmaf(-sy[i], d.y, fmaf(-sz[i], d.z, d.w)));
        if (e < emin[i]) { emin[i] = e; imin[i] = jg; } // strict < => 1st idx
      }
    }
    // wave argmin butterfly (lowest index wins ties)
    #pragma unroll
    for (int m = 1; m < 64; m <<= 1) {
      #pragma unroll
      for (int i = 0; i < 8; ++i) {
        float eo = __shfl_xor(emin[i], m, 64);
        int   io = __shfl_xor(imin[i], m, 64);
        if (eo < emin[i] || (eo == emin[i] && io < imin[i])) { emin[i] = eo; imin[i] = io; }
      }
    }

    #pragma unroll
    for (int i = 0; i < 8; ++i) {
      if (lane == i) { // leader lane i handles src point qbase+i
        float s2 = sx[i]*sx[i] + sy[i]*sy[i] + sz[i]*sz[i];
        float d2 = emin[i] + s2;
        float dist = sqrtf(fmaxf(d2, 0.f) + 1e-12f);
        int j = imin[i];
        float bx = B[3*j], by = B[3*j+1], bz = B[3*j+2];
        double* r = red1 + (wav * 8 + i) * 16;
        r[0]=sx[i]; r[1]=sy[i]; r[2]=sz[i];
        r[3]=bx;    r[4]=by;    r[5]=bz;
        r[6]=(double)sx[i]*bx;  r[7]=(double)sx[i]*by;  r[8]=(double)sx[i]*bz;
        r[9]=(double)sy[i]*bx;  r[10]=(double)sy[i]*by; r[11]=(double)sy[i]*bz;
        r[12]=(double)sz[i]*bx; r[13]=(double)sz[i]*by; r[14]=(double)sz[i]*bz;
        r[15]=dist;
      }
    }
    __syncthreads();
    if (tid < 16) {
      double ssum = 0.0;
      for (int g = 0; g < 32; ++g) ssum += red1[g * 16 + tid];
      atom_st(&partials[((size_t)par * NB + blk) * 16 + tid], ssum);
    }
    __syncthreads();      // partials stores drained (barrier waits vmcnt)
    if (tid == 0) {       // arrive, then wait for all 256 blocks
      __threadfence();    // release our partials at agent scope
      atomicAdd(&cnt[it], 1);
      u32 spins = 0;
      while (atom_ldi(&cnt[it]) < NB && spins < SPINCAP) {
        __builtin_amdgcn_s_sleep(1);
        ++spins;
      }
    }
    __syncthreads();
    __threadfence();      // acquire everyone's partials

    // ---- every block: reduce 256 partials, solve (deterministic) ----
    {
      double a2[16];
      #pragma unroll
      for (int k = 0; k < 16; ++k)
        a2[k] = atom_ld(&partials[((size_t)par * NB + tid) * 16 + k]);
      for (int m = 1; m < 64; m <<= 1) {
        #pragma unroll
        for (int k = 0; k < 16; ++k) a2[k] += __shfl_xor(a2[k], m, 64);
      }
      if (lane == 0)
        for (int k = 0; k < 16; ++k) red2[wav * 16 + k] = a2[k];
    }
    __syncthreads();
    if (tid == 0) {
      double S[16];
      for (int k = 0; k < 16; ++k)
        S[k] = red2[k] + red2[16+k] + red2[32+k] + red2[48+k];
      const double invN = 1.0 / NPTS;
      double cAv[3] = {S[0]*invN, S[1]*invN, S[2]*invN};
      double cBv[3] = {S[3]*invN, S[4]*invN, S[5]*invN};
      double H[3][3];
      for (int i = 0; i < 3; ++i)
        for (int j = 0; j < 3; ++j)
          H[i][j] = S[6 + i*3 + j] - (double)NPTS * cAv[i] * cBv[j];
      double err = S[15] * invN;
      int conv = (fabs(prev_err - err) < TOLER) ? 1 : 0;
      prev_err = err;
      double R[3][3];
      kabsch_R(H, R);
      double t0 = cBv[0] - (R[0][0]*cAv[0] + R[0][1]*cAv[1] + R[0][2]*cAv[2]);
      double t1 = cBv[1] - (R[1][0]*cAv[0] + R[1][1]*cAv[1] + R[1][2]*cAv[2]);
      double t2 = cBv[2] - (R[2][0]*cAv[0] + R[2][1]*cAv[1] + R[2][2]*cAv[2]);
      Tl[0]=(float)R[0][0]; Tl[1]=(float)R[0][1]; Tl[2]=(float)R[0][2];
      Tl[3]=(float)R[1][0]; Tl[4]=(float)R[1][1]; Tl[5]=(float)R[1][2];
      Tl[6]=(float)R[2][0]; Tl[7]=(float)R[2][1]; Tl[8]=(float)R[2][2];
      Tl[9]=(float)t0; Tl[10]=(float)t1; Tl[11]=(float)t2;
      dl = conv;
    }
    __syncthreads();
    { // apply T in fp32 (ref: new_src = T @ src in fp32, before done latches)
      float r00=Tl[0],r01=Tl[1],r02=Tl[2],r10=Tl[3],r11=Tl[4],r12=Tl[5];
      float r20=Tl[6],r21=Tl[7],r22=Tl[8],t0=Tl[9],t1=Tl[10],t2=Tl[11];
      int done = dl;
      #pragma unroll
      for (int i = 0; i < 8; ++i) {
        float nx = r00*sx[i] + r01*sy[i] + r02*sz[i] + t0;
        float ny = r10*sx[i] + r11*sy[i] + r12*sz[i] + t1;
        float nz = r20*sx[i] + r21*sy[i] + r22*sz[i] + t2;
        sx[i]=nx; sy[i]=ny; sz[i]=nz;
      }
      if (done) break; // uniform decision across all blocks
    }
  }

  // ---- final best_fit_transform(A, src): H = sum a (x) s - N cA cS^T ----
  // parity buffer not used by the last iteration's reads
  const int fpar = ((it == MAXIT) ? MAXIT : (it + 1)) & 1;
  __syncthreads();
  #pragma unroll
  for (int i = 0; i < 8; ++i) {
    if (lane == i) {
      double* r = red1 + (wav * 8 + i) * 16;
      r[0]=ax[i]; r[1]=ay[i]; r[2]=az[i];
      r[3]=sx[i]; r[4]=sy[i]; r[5]=sz[i];
      r[6]=(double)ax[i]*sx[i];  r[7]=(double)ax[i]*sy[i];  r[8]=(double)ax[i]*sz[i];
      r[9]=(double)ay[i]*sx[i];  r[10]=(double)ay[i]*sy[i]; r[11]=(double)ay[i]*sz[i];
      r[12]=(double)az[i]*sx[i]; r[13]=(double)az[i]*sy[i]; r[14]=(double)az[i]*sz[i];
      r[15]=0.0;
    }
  }
  __syncthreads();
  if (tid < 16) {
    double ssum = 0.0;
    for (int g = 0; g < 32; ++g) ssum += red1[g * 16 + tid];
    atom_st(&partials[((size_t)fpar * NB + blk) * 16 + tid], ssum);
  }
  __syncthreads();
  if (tid == 0) {
    __threadfence();
    atomicAdd(&cnt[MAXIT], 1);
  }
  if (blk != 0) return; // only block 0 produces the output

  if (tid == 0) {
    u32 spins = 0;
    while (atom_ldi(&cnt[MAXIT]) < NB && spins < SPINCAP) {
      __builtin_amdgcn_s_sleep(1);
      ++spins;
    }
  }
  __syncthreads();
  __threadfence();

  double a2[16];
  #pragma unroll
  for (int k = 0; k < 16; ++k)
    a2[k] = atom_ld(&partials[((size_t)fpar * NB + tid) * 16 + k]);
  for (int m = 1; m < 64; m <<= 1) {
    #pragma unroll
    for (int k = 0; k < 16; ++k) a2[k] += __shfl_xor(a2[k], m, 64);
  }
  if (lane == 0)
    for (int k = 0; k < 16; ++k) red2[wav * 16 + k] = a2[k];
  __syncthreads();
  if (tid == 0) {
    double S[16];
    for (int k = 0; k < 16; ++k)
      S[k] = red2[k] + red2[16+k] + red2[32+k] + red2[48+k];
    const double invN = 1.0 / NPTS;
    double cAv[3] = {S[0]*invN, S[1]*invN, S[2]*invN};
    double cSv[3] = {S[3]*invN, S[4]*invN, S[5]*invN};
    double H[3][3];
    for (int i = 0; i < 3; ++i)
      for (int j = 0; j < 3; ++j)
        H[i][j] = S[6 + i*3 + j] - (double)NPTS * cAv[i] * cSv[j];
    double R[3][3];
    kabsch_R(H, R);
    double u0 = cSv[0] - (R[0][0]*cAv[0] + R[0][1]*cAv[1] + R[0][2]*cAv[2]);
    double u1 = cSv[1] - (R[1][0]*cAv[0] + R[1][1]*cAv[1] + R[1][2]*cAv[2]);
    double u2 = cSv[2] - (R[2][0]*cAv[0] + R[2][1]*cAv[1] + R[2][2]*cAv[2]);
    out[0]=(float)R[0][0]; out[1]=(float)R[0][1]; out[2]=(float)R[0][2]; out[3]=(float)u0;
    out[4]=(float)R[1][0]; out[5]=(float)R[1][1]; out[6]=(float)R[1][2]; out[7]=(float)u1;
    out[8]=(float)R[2][0]; out[9]=(float)R[2][1]; out[10]=(float)R[2][2]; out[11]=(float)u2;
    out[12]=0.f; out[13]=0.f; out[14]=0.f; out[15]=1.f;
  }
}

extern "C" void kernel_launch(void* const* d_in, const int* in_sizes, int n_in,
                              void* d_out, int out_size, void* d_ws, size_t ws_size,
                              hipStream_t stream) {
  const float* A = (const float*)d_in[0];
  const float* B = (const float*)d_in[1];
  float* out = (float*)d_out;
  char* ws = (char*)d_ws; // needs ~66 KB

  hipLaunchKernelGGL(icp_init, dim3(1), dim3(64), 0, stream, ws);
  hipLaunchKernelGGL(icp_all, dim3(NB), dim3(NT), 0, stream, A, B, ws, out);
}

// Round 8
// 171.271 us; speedup vs baseline: 1.2777x; 1.1098x over previous
//
#include <hip/hip_runtime.h>

#define NPTS   8192
#define NB     256          // one block per CU (128KB LDS => 1 block/CU)
#define NT     256
#define NSTEP  (NPTS / 64)  // 128 inner steps per lane (full dst sweep)
#define MAXIT  20
#define TOLER  1e-3
#define SPINCAP 200000000u  // hang guard

typedef unsigned long long u64;
typedef unsigned int u32;

// ---- ws byte-offset layout (~67 KB) ----
// partials TRANSPOSED: double[2][16][NB]  (coalesced reduce reads)
#define WS_PART    0        // 2*16*256*8 = 65536 B
#define WS_FLAGS   65536    // int[NB] generation flags, 1024 B

__device__ inline double atom_ld(const double* p) {
  return __hip_atomic_load(p, __ATOMIC_RELAXED, __HIP_MEMORY_SCOPE_AGENT);
}
__device__ inline void atom_st(double* p, double v) {
  __hip_atomic_store(p, v, __ATOMIC_RELAXED, __HIP_MEMORY_SCOPE_AGENT);
}
__device__ inline int atom_ldi(const int* p) {
  return __hip_atomic_load(p, __ATOMIC_RELAXED, __HIP_MEMORY_SCOPE_AGENT);
}
__device__ inline void atom_sti(int* p, int v) {
  __hip_atomic_store(p, v, __ATOMIC_RELAXED, __HIP_MEMORY_SCOPE_AGENT);
}

// Analytic symmetric 3x3 eigendecomposition, eigenvalues DESCENDING,
// eigenvectors as columns of V. Deterministic (identical on every block).
__device__ void eig3_sym_desc(const double K[3][3], double w[3], double V[3][3])
{
  const double p1 = K[0][1]*K[0][1] + K[0][2]*K[0][2] + K[1][2]*K[1][2];
  const double q  = (K[0][0] + K[1][1] + K[2][2]) / 3.0;
  const double p2 = (K[0][0]-q)*(K[0][0]-q) + (K[1][1]-q)*(K[1][1]-q)
                  + (K[2][2]-q)*(K[2][2]-q) + 2.0*p1;
  if (p2 < 1e-280) { // K ~ q*I: any orthonormal basis
    w[0]=w[1]=w[2]=q;
    V[0][0]=1;V[1][0]=0;V[2][0]=0; V[0][1]=0;V[1][1]=1;V[2][1]=0;
    V[0][2]=0;V[1][2]=0;V[2][2]=1;
    return;
  }
  const double p = sqrt(p2 / 6.0);
  const double ip = 1.0 / p;
  double Bm[3][3];
  for (int i = 0; i < 3; ++i)
    for (int j = 0; j < 3; ++j)
      Bm[i][j] = (K[i][j] - ((i==j) ? q : 0.0)) * ip;
  double detB = Bm[0][0]*(Bm[1][1]*Bm[2][2] - Bm[1][2]*Bm[2][1])
              - Bm[0][1]*(Bm[1][0]*Bm[2][2] - Bm[1][2]*Bm[2][0])
              + Bm[0][2]*(Bm[1][0]*Bm[2][1] - Bm[1][1]*Bm[2][0]);
  double r = detB * 0.5;
  r = (r < -1.0) ? -1.0 : ((r > 1.0) ? 1.0 : r);
  const double phi = acos(r) / 3.0;
  w[0] = q + 2.0*p*cos(phi);                       // largest
  w[2] = q + 2.0*p*cos(phi + 2.0943951023931953);  // smallest (+2pi/3)
  w[1] = 3.0*q - w[0] - w[2];
  // eigenvectors for w[0], w[2] via best cross of rows of (K - lambda I)
  for (int kk = 0; kk < 2; ++kk) {
    const int k = (kk == 0) ? 0 : 2;
    double lam = w[k];
    double r0[3] = {K[0][0]-lam, K[0][1], K[0][2]};
    double r1[3] = {K[1][0], K[1][1]-lam, K[1][2]};
    double r2[3] = {K[2][0], K[2][1], K[2][2]-lam};
    double c01[3] = {r0[1]*r1[2]-r0[2]*r1[1], r0[2]*r1[0]-r0[0]*r1[2], r0[0]*r1[1]-r0[1]*r1[0]};
    double c12[3] = {r1[1]*r2[2]-r1[2]*r2[1], r1[2]*r2[0]-r1[0]*r2[2], r1[0]*r2[1]-r1[1]*r2[0]};
    double c20[3] = {r2[1]*r0[2]-r2[2]*r0[1], r2[2]*r0[0]-r2[0]*r0[2]*0 - r2[0]*r0[2] + r2[2]*r0[0]*0, 0};
    // (recompute c20 cleanly)
    c20[0] = r2[1]*r0[2] - r2[2]*r0[1];
    c20[1] = r2[2]*r0[0] - r2[0]*r0[2];
    c20[2] = r2[0]*r0[1] - r2[1]*r0[0];
    double n01 = c01[0]*c01[0]+c01[1]*c01[1]+c01[2]*c01[2];
    double n12 = c12[0]*c12[0]+c12[1]*c12[1]+c12[2]*c12[2];
    double n20 = c20[0]*c20[0]+c20[1]*c20[1]+c20[2]*c20[2];
    double* best = c01; double nb = n01;
    if (n12 > nb) { best = c12; nb = n12; }
    if (n20 > nb) { best = c20; nb = n20; }
    double inv = 1.0 / sqrt(nb + 1e-300);
    V[0][k]=best[0]*inv; V[1][k]=best[1]*inv; V[2][k]=best[2]*inv;
  }
  // middle eigenvector: orthogonal complement (sign irrelevant downstream)
  V[0][1] = V[1][2]*V[2][0] - V[2][2]*V[1][0];
  V[1][1] = V[2][2]*V[0][0] - V[0][2]*V[2][0];
  V[2][1] = V[0][2]*V[1][0] - V[1][2]*V[0][0];
  double nm = sqrt(V[0][1]*V[0][1]+V[1][1]*V[1][1]+V[2][1]*V[2][1]) + 1e-300;
  V[0][1] /= nm; V[1][1] /= nm; V[2][1] /= nm;
}

// Kabsch rotation from 3x3 cross-covariance H (double, single-thread):
// H = U S V^T (numpy convention), R = V' U^T with last V column flipped if
// det(V U^T) < 0 — matches the reference's Vt-last-row flip exactly.
// Eigen of H^T H gives V; U_k = normalize(H v_k). Eigenvector signs cancel
// in R0 = sum_k v_k u_k^T, so analytic sign ambiguity is harmless.
__device__ void kabsch_R(const double H[3][3], double R[3][3])
{
  double K[3][3]; // H^T H = V S^2 V^T
  for (int i = 0; i < 3; ++i)
    for (int j = 0; j < 3; ++j) {
      double s = 0.0;
      for (int k = 0; k < 3; ++k) s += H[k][i] * H[k][j];
      K[i][j] = s;
    }
  double w[3], V[3][3];
  eig3_sym_desc(K, w, V);
  double U[3][3]; // columns u_k = normalize(H v_k)
  for (int k = 0; k < 3; ++k) {
    double u0 = H[0][0]*V[0][k] + H[0][1]*V[1][k] + H[0][2]*V[2][k];
    double u1 = H[1][0]*V[0][k] + H[1][1]*V[1][k] + H[1][2]*V[2][k];
    double u2 = H[2][0]*V[0][k] + H[2][1]*V[1][k] + H[2][2]*V[2][k];
    double n = sqrt(u0*u0 + u1*u1 + u2*u2);
    if (n > 1e-150) { u0 /= n; u1 /= n; u2 /= n; }
    else if (k == 2) { // degenerate smallest sv: complete basis
      u0 = U[1][0]*U[2][1] - U[2][0]*U[1][1];
      u1 = U[2][0]*U[0][1] - U[0][0]*U[2][1];
      u2 = U[0][0]*U[1][1] - U[1][0]*U[0][1];
      double n2 = sqrt(u0*u0 + u1*u1 + u2*u2) + 1e-300;
      u0 /= n2; u1 /= n2; u2 /= n2;
    } else {
      u0 = (k == 0) ? 1.0 : 0.0; u1 = (k == 1) ? 1.0 : 0.0; u2 = 0.0;
    }
    U[0][k] = u0; U[1][k] = u1; U[2][k] = u2;
  }
  double R0[3][3]; // V U^T
  for (int i = 0; i < 3; ++i)
    for (int j = 0; j < 3; ++j)
      R0[i][j] = V[i][0]*U[j][0] + V[i][1]*U[j][1] + V[i][2]*U[j][2];
  double det = R0[0][0]*(R0[1][1]*R0[2][2] - R0[1][2]*R0[2][1])
             - R0[0][1]*(R0[1][0]*R0[2][2] - R0[1][2]*R0[2][0])
             + R0[0][2]*(R0[1][0]*R0[2][1] - R0[1][1]*R0[2][0]);
  if (det < 0.0)
    for (int i = 0; i < 3; ++i)
      for (int j = 0; j < 3; ++j)
        R0[i][j] -= 2.0 * V[i][2] * U[j][2]; // flip last column of V
  for (int i = 0; i < 3; ++i)
    for (int j = 0; j < 3; ++j)
      R[i][j] = R0[i][j];
}

__global__ void icp_init(char* __restrict__ ws)
{
  ((int*)(ws + WS_FLAGS))[threadIdx.x] = 0; // 256 generation flags
}

// Generation-flag grid barrier: each block stores its own flag (no RMW
// contention); wave 0 polls all 256 flags for >= gen. Caller must fence
// before the flag store (release) and after return (acquire).
__device__ inline void flag_barrier(int* flags, int blk, int gen,
                                    int tid, int wav, int lane)
{
  __syncthreads();            // all partial stores in this block drained
  if (tid == 0) {
    __threadfence();          // release partials at agent scope
    atom_sti(&flags[blk], gen);
  }
  if (wav == 0) {
    const int base = lane * 4;
    u32 spins = 0;
    bool ok = false;
    while (!ok && spins < SPINCAP) {
      int f0 = atom_ldi(&flags[base + 0]);
      int f1 = atom_ldi(&flags[base + 1]);
      int f2 = atom_ldi(&flags[base + 2]);
      int f3 = atom_ldi(&flags[base + 3]);
      ok = __all((f0 >= gen) && (f1 >= gen) && (f2 >= gen) && (f3 >= gen));
      ++spins;
    }
  }
  __syncthreads();
  __threadfence();            // acquire everyone's partials
}

// Persistent kernel: Bp staged into LDS ONCE; all 20 iterations + final
// best-fit. block b owns src points b*32..b*32+31 (wave w: 8, in registers).
// Every block redundantly reduces+solves (deterministic => identical T/done).
__global__ __launch_bounds__(NT, 1)
void icp_all(const float* __restrict__ A, const float* __restrict__ B,
             char* __restrict__ ws, float* __restrict__ out)
{
  double* partials = (double*)(ws + WS_PART); // [2][16][NB]
  int*    flags    = (int*)(ws + WS_FLAGS);

  __shared__ __align__(16) float4 bp_lds[NPTS];   // 128 KB, persistent
  __shared__ double red1[32 * 16];                // leader rows
  __shared__ double red2[4 * 16];                 // wave sums
  __shared__ float  Tl[12];
  __shared__ int    dl;

  const int tid  = threadIdx.x;
  const int blk  = blockIdx.x;
  const int wav  = tid >> 6;
  const int lane = tid & 63;
  const int qbase = blk * 32 + wav * 8; // this wave's 8 src points

  // ---- stage Bp once (B is constant across all iterations) ----
  for (int i = tid; i < NPTS; i += NT) {
    float bx = B[3*i], by = B[3*i+1], bz = B[3*i+2];
    bp_lds[i] = make_float4(2.f*bx, 2.f*by, 2.f*bz, bx*bx + by*by + bz*bz);
  }

  float ax[8], ay[8], az[8], sx[8], sy[8], sz[8];
  #pragma unroll
  for (int i = 0; i < 8; ++i) { // broadcast loads: all lanes hold all 8 src
    int p = qbase + i;
    ax[i] = A[3*p]; ay[i] = A[3*p+1]; az[i] = A[3*p+2];
    sx[i] = ax[i];  sy[i] = ay[i];    sz[i] = az[i];
  }
  __syncthreads(); // bp_lds ready

  double prev_err = 0.0; // tid0-meaningful; identical on every block
  int it = 0;
  for (; it < MAXIT; ++it) {
    const int par = it & 1;
    // ---- brute-force 1-NN: persistent LDS dst, explicit prefetch ----
    float emin[8]; int imin[8];
    #pragma unroll
    for (int i = 0; i < 8; ++i) { emin[i] = 3.4e38f; imin[i] = 0; }

    float4 dcur = bp_lds[lane];
    #pragma unroll 4
    for (int stp = 0; stp < NSTEP - 1; ++stp) {
      float4 dnxt = bp_lds[(stp + 1) * 64 + lane]; // prefetch next
      const int jg = stp * 64 + lane;
      #pragma unroll
      for (int i = 0; i < 8; ++i) {
        // e = |b|^2 - 2 s.b ; argmin_j e == argmin_j d2 (d2 = e + |s|^2)
        float e = fmaf(-sx[i], dcur.x, fmaf(-sy[i], dcur.y, fmaf(-sz[i], dcur.z, dcur.w)));
        if (e < emin[i]) { emin[i] = e; imin[i] = jg; } // strict < => 1st idx
      }
      dcur = dnxt;
    }
    { // epilogue step
      const int jg = (NSTEP - 1) * 64 + lane;
      #pragma unroll
      for (int i = 0; i < 8; ++i) {
        float e = fmaf(-sx[i], dcur.x, fmaf(-sy[i], dcur.y, fmaf(-sz[i], dcur.z, dcur.w)));
        if (e < emin[i]) { emin[i] = e; imin[i] = jg; }
      }
    }
    // wave argmin butterfly (lowest index wins ties)
    #pragma unroll
    for (int m = 1; m < 64; m <<= 1) {
      #pragma unroll
      for (int i = 0; i < 8; ++i) {
        float eo = __shfl_xor(emin[i], m, 64);
        int   io = __shfl_xor(imin[i], m, 64);
        if (eo < emin[i] || (eo == emin[i] && io < imin[i])) { emin[i] = eo; imin[i] = io; }
      }
    }

    #pragma unroll
    for (int i = 0; i < 8; ++i) {
      if (lane == i) { // leader lane i handles src point qbase+i
        float s2 = sx[i]*sx[i] + sy[i]*sy[i] + sz[i]*sz[i];
        float d2 = emin[i] + s2;
        float dist = sqrtf(fmaxf(d2, 0.f) + 1e-12f);
        int j = imin[i];
        float bx = B[3*j], by = B[3*j+1], bz = B[3*j+2];
        double* r = red1 + (wav * 8 + i) * 16;
        r[0]=sx[i]; r[1]=sy[i]; r[2]=sz[i];
        r[3]=bx;    r[4]=by;    r[5]=bz;
        r[6]=(double)sx[i]*bx;  r[7]=(double)sx[i]*by;  r[8]=(double)sx[i]*bz;
        r[9]=(double)sy[i]*bx;  r[10]=(double)sy[i]*by; r[11]=(double)sy[i]*bz;
        r[12]=(double)sz[i]*bx; r[13]=(double)sz[i]*by; r[14]=(double)sz[i]*bz;
        r[15]=dist;
      }
    }
    __syncthreads();
    if (tid < 16) { // transposed store: partials[par][k=tid][blk]
      double ssum = 0.0;
      for (int g = 0; g < 32; ++g) ssum += red1[g * 16 + tid];
      atom_st(&partials[((size_t)par * 16 + tid) * NB + blk], ssum);
    }
    flag_barrier(flags, blk, it + 1, tid, wav, lane);

    // ---- every block: reduce 256 partials (coalesced), solve ----
    {
      double a2[16];
      #pragma unroll
      for (int k = 0; k < 16; ++k) // thread t reads column t of row k
        a2[k] = atom_ld(&partials[((size_t)par * 16 + k) * NB + tid]);
      for (int m = 1; m < 64; m <<= 1) {
        #pragma unroll
        for (int k = 0; k < 16; ++k) a2[k] += __shfl_xor(a2[k], m, 64);
      }
      if (lane == 0)
        for (int k = 0; k < 16; ++k) red2[wav * 16 + k] = a2[k];
    }
    __syncthreads();
    if (tid == 0) {
      double S[16];
      for (int k = 0; k < 16; ++k)
        S[k] = red2[k] + red2[16+k] + red2[32+k] + red2[48+k];
      const double invN = 1.0 / NPTS;
      double cAv[3] = {S[0]*invN, S[1]*invN, S[2]*invN};
      double cBv[3] = {S[3]*invN, S[4]*invN, S[5]*invN};
      double H[3][3];
      for (int i = 0; i < 3; ++i)
        for (int j = 0; j < 3; ++j)
          H[i][j] = S[6 + i*3 + j] - (double)NPTS * cAv[i] * cBv[j];
      double err = S[15] * invN;
      int conv = (fabs(prev_err - err) < TOLER) ? 1 : 0;
      prev_err = err;
      double R[3][3];
      kabsch_R(H, R);
      double t0 = cBv[0] - (R[0][0]*cAv[0] + R[0][1]*cAv[1] + R[0][2]*cAv[2]);
      double t1 = cBv[1] - (R[1][0]*cAv[0] + R[1][1]*cAv[1] + R[1][2]*cAv[2]);
      double t2 = cBv[2] - (R[2][0]*cAv[0] + R[2][1]*cAv[1] + R[2][2]*cAv[2]);
      Tl[0]=(float)R[0][0]; Tl[1]=(float)R[0][1]; Tl[2]=(float)R[0][2];
      Tl[3]=(float)R[1][0]; Tl[4]=(float)R[1][1]; Tl[5]=(float)R[1][2];
      Tl[6]=(float)R[2][0]; Tl[7]=(float)R[2][1]; Tl[8]=(float)R[2][2];
      Tl[9]=(float)t0; Tl[10]=(float)t1; Tl[11]=(float)t2;
      dl = conv;
    }
    __syncthreads();
    { // apply T in fp32 (ref: new_src = T @ src in fp32, before done latches)
      float r00=Tl[0],r01=Tl[1],r02=Tl[2],r10=Tl[3],r11=Tl[4],r12=Tl[5];
      float r20=Tl[6],r21=Tl[7],r22=Tl[8],t0=Tl[9],t1=Tl[10],t2=Tl[11];
      int done = dl;
      #pragma unroll
      for (int i = 0; i < 8; ++i) {
        float nx = r00*sx[i] + r01*sy[i] + r02*sz[i] + t0;
        float ny = r10*sx[i] + r11*sy[i] + r12*sz[i] + t1;
        float nz = r20*sx[i] + r21*sy[i] + r22*sz[i] + t2;
        sx[i]=nx; sy[i]=ny; sz[i]=nz;
      }
      if (done) break; // uniform decision across all blocks
    }
  }

  // ---- final best_fit_transform(A, src): H = sum a (x) s - N cA cS^T ----
  const int  fpar = (it < MAXIT) ? ((it + 1) & 1) : (MAXIT & 1);
  const int  fgen = (it < MAXIT) ? (it + 2) : (MAXIT + 1);
  __syncthreads();
  #pragma unroll
  for (int i = 0; i < 8; ++i) {
    if (lane == i) {
      double* r = red1 + (wav * 8 + i) * 16;
      r[0]=ax[i]; r[1]=ay[i]; r[2]=az[i];
      r[3]=sx[i]; r[4]=sy[i]; r[5]=sz[i];
      r[6]=(double)ax[i]*sx[i];  r[7]=(double)ax[i]*sy[i];  r[8]=(double)ax[i]*sz[i];
      r[9]=(double)ay[i]*sx[i];  r[10]=(double)ay[i]*sy[i]; r[11]=(double)ay[i]*sz[i];
      r[12]=(double)az[i]*sx[i]; r[13]=(double)az[i]*sy[i]; r[14]=(double)az[i]*sz[i];
      r[15]=0.0;
    }
  }
  __syncthreads();
  if (tid < 16) {
    double ssum = 0.0;
    for (int g = 0; g < 32; ++g) ssum += red1[g * 16 + tid];
    atom_st(&partials[((size_t)fpar * 16 + tid) * NB + blk], ssum);
  }
  if (blk != 0) { // non-output blocks: just arrive (release) and exit
    __syncthreads();
    if (tid == 0) { __threadfence(); atom_sti(&flags[blk], fgen); }
    return;
  }
  flag_barrier(flags, blk, fgen, tid, wav, lane);

  double a2[16];
  #pragma unroll
  for (int k = 0; k < 16; ++k)
    a2[k] = atom_ld(&partials[((size_t)fpar * 16 + k) * NB + tid]);
  for (int m = 1; m < 64; m <<= 1) {
    #pragma unroll
    for (int k = 0; k < 16; ++k) a2[k] += __shfl_xor(a2[k], m, 64);
  }
  if (lane == 0)
    for (int k = 0; k < 16; ++k) red2[wav * 16 + k] = a2[k];
  __syncthreads();
  if (tid == 0) {
    double S[16];
    for (int k = 0; k < 16; ++k)
      S[k] = red2[k] + red2[16+k] + red2[32+k] + red2[48+k];
    const double invN = 1.0 / NPTS;
    double cAv[3] = {S[0]*invN, S[1]*invN, S[2]*invN};
    double cSv[3] = {S[3]*invN, S[4]*invN, S[5]*invN};
    double H[3][3];
    for (int i = 0; i < 3; ++i)
      for (int j = 0; j < 3; ++j)
        H[i][j] = S[6 + i*3 + j] - (double)NPTS * cAv[i] * cSv[j];
    double R[3][3];
    kabsch_R(H, R);
    double u0 = cSv[0] - (R[0][0]*cAv[0] + R[0][1]*cAv[1] + R[0][2]*cAv[2]);
    double u1 = cSv[1] - (R[1][0]*cAv[0] + R[1][1]*cAv[1] + R[1][2]*cAv[2]);
    double u2 = cSv[2] - (R[2][0]*cAv[0] + R[2][1]*cAv[1] + R[2][2]*cAv[2]);
    out[0]=(float)R[0][0]; out[1]=(float)R[0][1]; out[2]=(float)R[0][2]; out[3]=(float)u0;
    out[4]=(float)R[1][0]; out[5]=(float)R[1][1]; out[6]=(float)R[1][2]; out[7]=(float)u1;
    out[8]=(float)R[2][0]; out[9]=(float)R[2][1]; out[10]=(float)R[2][2]; out[11]=(float)u2;
    out[12]=0.f; out[13]=0.f; out[14]=0.f; out[15]=1.f;
  }
}

extern "C" void kernel_launch(void* const* d_in, const int* in_sizes, int n_in,
                              void* d_out, int out_size, void* d_ws, size_t ws_size,
                              hipStream_t stream) {
  const float* A = (const float*)d_in[0];
  const float* B = (const float*)d_in[1];
  float* out = (float*)d_out;
  char* ws = (char*)d_ws; // needs ~67 KB

  hipLaunchKernelGGL(icp_init, dim3(1), dim3(NT), 0, stream, ws);
  hipLaunchKernelGGL(icp_all, dim3(NB), dim3(NT), 0, stream, A, B, ws, out);
}